// Round 13
// baseline (139.828 us; speedup 1.0000x reference)
//
#include <hip/hip_runtime.h>
#include <hip/hip_fp16.h>
#include <hip/hip_cooperative_groups.h>

namespace cg = cooperative_groups;

#define BATCH 128
#define NC1   1152
#define ND1   8
#define NC2   10
#define ND2   16
#define SDIM  (NC2 * ND2)    // 160
#define HALFC (NC1 / 2)      // 576
#define CPH   18             // caps per 16-lane group (576/32)

// kernel B tiling
#define CB 16                // caps per block
#define BB 32                // batch per block

__device__ __forceinline__ unsigned pack_h2(float a, float b) {
    __half2 h = __floats2half2_rn(a, b);
    return *reinterpret_cast<unsigned*>(&h);
}
__device__ __forceinline__ float2 unpack_h2(unsigned v) {
    __half2 h = *reinterpret_cast<__half2*>(&v);
    return __half22float2(h);
}
__device__ __forceinline__ unsigned pmul_h2(unsigned a, unsigned b) {
    __half2 ha = *reinterpret_cast<__half2*>(&a);
    __half2 hb = *reinterpret_cast<__half2*>(&b);
    __half2 r = __hmul2(ha, hb);
    return *reinterpret_cast<unsigned*>(&r);
}
__device__ __forceinline__ unsigned padd_h2(unsigned a, unsigned b) {
    __half2 ha = *reinterpret_cast<__half2*>(&a);
    __half2 hb = *reinterpret_cast<__half2*>(&b);
    __half2 r = __hadd2(ha, hb);
    return *reinterpret_cast<unsigned*>(&r);
}

// DPP row-rotate (within 16-lane row) on the VALU pipe.
template<int CTRL>
__device__ __forceinline__ unsigned dpp_mov(unsigned v) {
    return (unsigned)__builtin_amdgcn_mov_dpp((int)v, CTRL, 0xF, 0xF, true);
}
__device__ __forceinline__ unsigned row_reduce_h2(unsigned t2) {
    t2 = padd_h2(t2, dpp_mov<0x128>(t2));   // ror 8
    t2 = padd_h2(t2, dpp_mov<0x124>(t2));   // ror 4
    t2 = padd_h2(t2, dpp_mov<0x122>(t2));   // ror 2
    t2 = padd_h2(t2, dpp_mov<0x121>(t2));   // ror 1
    return t2;
}

// ---- zero the s0 accumulator (atomics target) ---------------------------
__global__ void caps_zero(float* __restrict__ s0) {
    s0[blockIdx.x * 256 + threadIdx.x] = 0.0f;   // 80 x 256 = 20480
}

// ---- Kernel B: u_hat (f16x2 -> ws) + pass-0 sum via atomics -------------
// Round-12 version (f16-packed W, 2 blocks/CU) -- proven at parity.
__global__ __launch_bounds__(256, 2) void caps_uhat(
    const float* __restrict__ x,     // [B, C1*D1]
    const float* __restrict__ W,     // [C1, C2, D2, D1]
    unsigned* __restrict__ u_ws,     // [B][5][C1][16]
    float* __restrict__ s0)          // [B][SDIM] (pre-zeroed)
{
    const int cb  = blockIdx.x;      // 0..71
    const int bb  = blockIdx.y;      // 0..3
    const int tid = threadIdx.x;
    const int cl  = tid >> 4;        // 0..15
    const int d   = tid & 15;
    const int wl  = tid & 63;        // lane in wave

    __shared__ float prim[BB][CB][ND1];  // 16 KB

    for (int i = tid; i < BB * CB; i += 256) {
        const int b = i >> 4, c = i & 15;
        const float* xr = x + ((size_t)(bb * BB + b) * NC1 + (cb * CB + c)) * ND1;
        float4 a0 = *(const float4*)(xr);
        float4 a1 = *(const float4*)(xr + 4);
        float sq = a0.x*a0.x + a0.y*a0.y + a0.z*a0.z + a0.w*a0.w
                 + a1.x*a1.x + a1.y*a1.y + a1.z*a1.z + a1.w*a1.w;
        float g = (sq / (1.0f + sq)) * rsqrtf(sq + 1e-8f);
        prim[b][c][0] = a0.x * g; prim[b][c][1] = a0.y * g;
        prim[b][c][2] = a0.z * g; prim[b][c][3] = a0.w * g;
        prim[b][c][4] = a1.x * g; prim[b][c][5] = a1.y * g;
        prim[b][c][6] = a1.z * g; prim[b][c][7] = a1.w * g;
    }
    __syncthreads();

    const int c_glob = cb * CB + cl;
    unsigned wpk[NC2][4];   // W[c,:,d,:] packed f16x2: 40 VGPRs
    #pragma unroll
    for (int j = 0; j < NC2; ++j) {
        const float* Wr = W + (((size_t)c_glob * NC2 + j) * ND2 + d) * ND1;
        float4 w0 = *(const float4*)(Wr);
        float4 w1 = *(const float4*)(Wr + 4);
        wpk[j][0] = pack_h2(w0.x, w0.y);
        wpk[j][1] = pack_h2(w0.z, w0.w);
        wpk[j][2] = pack_h2(w1.x, w1.y);
        wpk[j][3] = pack_h2(w1.z, w1.w);
    }

    for (int k = 0; k < BB; ++k) {
        const int b = (k + cb) & (BB - 1);
        const int bglob = bb * BB + b;
        float p[ND1];
        #pragma unroll
        for (int kk = 0; kk < ND1; ++kk) p[kk] = prim[b][cl][kk];

        unsigned* ur = u_ws + ((size_t)bglob * 5 * NC1 + c_glob) * 16 + d;
        #pragma unroll
        for (int jp = 0; jp < 5; ++jp) {
            float u0 = 0.f, u1 = 0.f;
            #pragma unroll
            for (int kp = 0; kp < 4; ++kp) {
                float2 fa = unpack_h2(wpk[2*jp  ][kp]);
                float2 fb = unpack_h2(wpk[2*jp+1][kp]);
                u0 += fa.x * p[2*kp] + fa.y * p[2*kp+1];
                u1 += fb.x * p[2*kp] + fb.y * p[2*kp+1];
            }
            unsigned pk = pack_h2(u0, u1);
            ur[(size_t)jp * (NC1 * 16)] = pk;
            pk = padd_h2(pk, (unsigned)__shfl_xor((int)pk, 16));
            pk = padd_h2(pk, (unsigned)__shfl_xor((int)pk, 32));
            if (wl < 16) {
                float2 f = unpack_h2(pk);
                atomicAdd(&s0[(size_t)bglob * SDIM + (2*jp)   * 16 + d], f.x);
                atomicAdd(&s0[(size_t)bglob * SDIM + (2*jp+1) * 16 + d], f.y);
            }
        }
    }
}

// ---- cooperative double-pass routing: u read ONCE, held in registers -----
// 256 blocks (b = blk>>1, half h = blk&1) x 512 thr = 32 groups x 16 lanes.
// Group owns 18 caps -> 90 packed-u dwords/thread, all statically indexed.
// __launch_bounds__(512,1): VGPR cap 256 (round-5 spilled at the (512,2)
// cap of 128 -- this is the fix). Proven coop envelope: 256 blocks.
__global__ __launch_bounds__(512, 1) void caps_route2(
    const unsigned* __restrict__ u_ws,  // [B][5][C1][16] f16x2
    const float* __restrict__ s0,       // [B][SDIM]
    const float* __restrict__ bias,     // [SDIM]
    float* __restrict__ spart1,         // [B][2][SDIM]
    float* __restrict__ spart2,         // [B][2][SDIM]
    float* __restrict__ out)            // [B][SDIM]
{
    const int blk  = blockIdx.x;
    const int b    = blk >> 1;
    const int h    = blk & 1;
    const int tid  = threadIdx.x;
    const int grp  = tid >> 4;   // 0..31
    const int d    = tid & 15;
    const int wave = tid >> 6;   // 0..7

    __shared__ float vl[SDIM];
    __shared__ float sred[8][SDIM];

    cg::grid_group grid = cg::this_grid();

    // ---- load all u for this thread's 18 caps (90 dwords, static) ----
    const unsigned* ub = u_ws + (size_t)b * 5 * NC1 * 16 + d;
    const int c0 = h * HALFC + grp;      // caps c0 + i*32, i < 18
    unsigned uo[CPH][5];
    #pragma unroll
    for (int i = 0; i < CPH; ++i) {
        const int c = c0 + i * 32;
        #pragma unroll
        for (int jp = 0; jp < 5; ++jp)
            uo[i][jp] = ub[(size_t)jp * (NC1 * 16) + (size_t)c * 16];
    }

    // ---- v0 = squash(0.1*s0 + bias) ----
    if (tid < SDIM) {
        float s_a = 0.1f * s0[(size_t)b * SDIM + tid] + bias[tid];
        float qa = s_a * s_a;
        qa += __shfl_xor(qa, 1); qa += __shfl_xor(qa, 2);
        qa += __shfl_xor(qa, 4); qa += __shfl_xor(qa, 8);
        vl[tid] = (qa / (1.0f + qa)) * rsqrtf(qa + 1e-8f) * s_a;
    }
    __syncthreads();

    unsigned vsf[5];
    #pragma unroll
    for (int jp = 0; jp < 5; ++jp)
        vsf[jp] = pack_h2(vl[(2*jp)*16 + d], vl[(2*jp+1)*16 + d]);

    float sp[NC2];

    // ================= pass 1 (from registers) =================
    #pragma unroll
    for (int j = 0; j < NC2; ++j) sp[j] = 0.0f;
    #pragma unroll
    for (int i = 0; i < CPH; ++i) {
        float u[NC2], r[NC2];
        #pragma unroll
        for (int jp = 0; jp < 5; ++jp) {
            float2 f = unpack_h2(uo[i][jp]);
            u[2*jp] = f.x; u[2*jp+1] = f.y;
            unsigned t2 = row_reduce_h2(pmul_h2(uo[i][jp], vsf[jp]));
            float2 rr = unpack_h2(t2);
            r[2*jp] = rr.x; r[2*jp+1] = rr.y;
        }
        float ssum = 0.0f;
        #pragma unroll
        for (int j = 0; j < NC2; ++j) { r[j] = __expf(r[j]); ssum += r[j]; }
        float inv = 1.0f / ssum;
        #pragma unroll
        for (int j = 0; j < NC2; ++j) sp[j] += (r[j] * inv) * u[j];
    }
    #pragma unroll
    for (int j = 0; j < NC2; ++j) {
        sp[j] += __shfl_xor(sp[j], 16);
        sp[j] += __shfl_xor(sp[j], 32);
    }
    if ((tid & 63) < 16) {
        #pragma unroll
        for (int j = 0; j < NC2; ++j) sred[wave][j * 16 + d] = sp[j];
    }
    __syncthreads();
    if (tid < SDIM) {
        float acc = 0.0f;
        #pragma unroll
        for (int w = 0; w < 8; ++w) acc += sred[w][tid];
        spart1[(size_t)(b * 2 + h) * SDIM + tid] = acc;
    }

    grid.sync();

    // ---- v = v0 + squash(sum spart1 + bias) ----
    if (tid < SDIM) {
        float bv = bias[tid];
        float s_a = 0.1f * s0[(size_t)b * SDIM + tid] + bv;
        float qa = s_a * s_a;
        qa += __shfl_xor(qa, 1); qa += __shfl_xor(qa, 2);
        qa += __shfl_xor(qa, 4); qa += __shfl_xor(qa, 8);
        float v = (qa / (1.0f + qa)) * rsqrtf(qa + 1e-8f) * s_a;
        float s_b = spart1[(size_t)(b * 2 + 0) * SDIM + tid]
                  + spart1[(size_t)(b * 2 + 1) * SDIM + tid] + bv;
        float qb = s_b * s_b;
        qb += __shfl_xor(qb, 1); qb += __shfl_xor(qb, 2);
        qb += __shfl_xor(qb, 4); qb += __shfl_xor(qb, 8);
        v += (qb / (1.0f + qb)) * rsqrtf(qb + 1e-8f) * s_b;
        vl[tid] = v;
    }
    __syncthreads();

    #pragma unroll
    for (int jp = 0; jp < 5; ++jp)
        vsf[jp] = pack_h2(vl[(2*jp)*16 + d], vl[(2*jp+1)*16 + d]);

    // ================= pass 2 (from registers) =================
    #pragma unroll
    for (int j = 0; j < NC2; ++j) sp[j] = 0.0f;
    #pragma unroll
    for (int i = 0; i < CPH; ++i) {
        float u[NC2], r[NC2];
        #pragma unroll
        for (int jp = 0; jp < 5; ++jp) {
            float2 f = unpack_h2(uo[i][jp]);
            u[2*jp] = f.x; u[2*jp+1] = f.y;
            unsigned t2 = row_reduce_h2(pmul_h2(uo[i][jp], vsf[jp]));
            float2 rr = unpack_h2(t2);
            r[2*jp] = rr.x; r[2*jp+1] = rr.y;
        }
        float ssum = 0.0f;
        #pragma unroll
        for (int j = 0; j < NC2; ++j) { r[j] = __expf(r[j]); ssum += r[j]; }
        float inv = 1.0f / ssum;
        #pragma unroll
        for (int j = 0; j < NC2; ++j) sp[j] += (r[j] * inv) * u[j];
    }
    #pragma unroll
    for (int j = 0; j < NC2; ++j) {
        sp[j] += __shfl_xor(sp[j], 16);
        sp[j] += __shfl_xor(sp[j], 32);
    }
    if ((tid & 63) < 16) {
        #pragma unroll
        for (int j = 0; j < NC2; ++j) sred[wave][j * 16 + d] = sp[j];
    }
    __syncthreads();
    if (tid < SDIM) {
        float acc = 0.0f;
        #pragma unroll
        for (int w = 0; w < 8; ++w) acc += sred[w][tid];
        spart2[(size_t)(b * 2 + h) * SDIM + tid] = acc;
    }

    grid.sync();

    // ---- final combine (half 0 writes out) ----
    if (h == 0 && tid < SDIM) {
        float s = spart2[(size_t)(b * 2 + 0) * SDIM + tid]
                + spart2[(size_t)(b * 2 + 1) * SDIM + tid] + bias[tid];
        float sq = s * s;
        sq += __shfl_xor(sq, 1); sq += __shfl_xor(sq, 2);
        sq += __shfl_xor(sq, 4); sq += __shfl_xor(sq, 8);
        out[(size_t)b * SDIM + tid] = (sq / (1.0f + sq)) * rsqrtf(sq + 1e-8f) * s;
    }
}

// ---- Fallback: round-1 fused kernel (proven, 198 us) ---------------------
__global__ __launch_bounds__(1024) void caps_fused(
    const float* __restrict__ x, const float* __restrict__ W,
    const float* __restrict__ bias, float* __restrict__ out)
{
    const int b    = blockIdx.x;
    const int tid  = threadIdx.x;
    const int grp  = tid >> 4;
    const int d    = tid & 15;
    const int wave = tid >> 6;
    const int lane = tid & 63;

    __shared__ float prim[NC1][ND1];
    __shared__ float sred[16][SDIM];
    __shared__ float vbuf[SDIM];

    const float* xb = x + (size_t)b * (NC1 * ND1);
    for (int c = tid; c < NC1; c += 1024) {
        float4 a0 = *(const float4*)(xb + c * 8);
        float4 a1 = *(const float4*)(xb + c * 8 + 4);
        float sq = a0.x*a0.x + a0.y*a0.y + a0.z*a0.z + a0.w*a0.w
                 + a1.x*a1.x + a1.y*a1.y + a1.z*a1.z + a1.w*a1.w;
        float g = (sq / (1.0f + sq)) * rsqrtf(sq + 1e-8f);
        prim[c][0] = a0.x * g; prim[c][1] = a0.y * g;
        prim[c][2] = a0.z * g; prim[c][3] = a0.w * g;
        prim[c][4] = a1.x * g; prim[c][5] = a1.y * g;
        prim[c][6] = a1.z * g; prim[c][7] = a1.w * g;
    }
    __syncthreads();

    float vsum[NC2], sp[NC2];
    for (int pass = 0; pass < 3; ++pass) {
        #pragma unroll
        for (int j = 0; j < NC2; ++j) sp[j] = 0.0f;
        for (int c = grp; c < NC1; c += 64) {
            float p[8];
            #pragma unroll
            for (int k = 0; k < 8; ++k) p[k] = prim[c][k];
            const float* Wc = W + (size_t)c * (NC2 * ND2 * ND1) + d * ND1;
            float u[NC2];
            #pragma unroll
            for (int j = 0; j < NC2; ++j) {
                const float4 w0 = *(const float4*)(Wc + j * (ND2 * ND1));
                const float4 w1 = *(const float4*)(Wc + j * (ND2 * ND1) + 4);
                u[j] = w0.x*p[0] + w0.y*p[1] + w0.z*p[2] + w0.w*p[3]
                     + w1.x*p[4] + w1.y*p[5] + w1.z*p[6] + w1.w*p[7];
            }
            if (pass == 0) {
                #pragma unroll
                for (int j = 0; j < NC2; ++j) sp[j] += u[j];
            } else {
                float r[NC2];
                #pragma unroll
                for (int j = 0; j < NC2; ++j) {
                    float t = u[j] * vsum[j];
                    t += __shfl_xor(t, 1); t += __shfl_xor(t, 2);
                    t += __shfl_xor(t, 4); t += __shfl_xor(t, 8);
                    r[j] = t;
                }
                float m = r[0];
                #pragma unroll
                for (int j = 1; j < NC2; ++j) m = fmaxf(m, r[j]);
                float ssum = 0.0f;
                #pragma unroll
                for (int j = 0; j < NC2; ++j) { r[j] = __expf(r[j] - m); ssum += r[j]; }
                float inv = 1.0f / ssum;
                #pragma unroll
                for (int j = 0; j < NC2; ++j) sp[j] += (r[j] * inv) * u[j];
            }
        }
        #pragma unroll
        for (int j = 0; j < NC2; ++j) {
            sp[j] += __shfl_xor(sp[j], 16);
            sp[j] += __shfl_xor(sp[j], 32);
        }
        if (lane < 16) {
            #pragma unroll
            for (int j = 0; j < NC2; ++j) sred[wave][j * 16 + d] = sp[j];
        }
        __syncthreads();
        if (tid < SDIM) {
            float acc = 0.0f;
            #pragma unroll
            for (int w = 0; w < 16; ++w) acc += sred[w][tid];
            float s = bias[tid] + (pass == 0 ? 0.1f * acc : acc);
            float sq = s * s;
            sq += __shfl_xor(sq, 1); sq += __shfl_xor(sq, 2);
            sq += __shfl_xor(sq, 4); sq += __shfl_xor(sq, 8);
            float vv = (sq / (1.0f + sq)) * rsqrtf(sq + 1e-8f) * s;
            if (pass == 2) out[(size_t)b * SDIM + tid] = vv;
            else           vbuf[tid] = vv;
        }
        __syncthreads();
        if (pass < 2) {
            #pragma unroll
            for (int j = 0; j < NC2; ++j) {
                float vv = vbuf[j * 16 + d];
                vsum[j] = (pass == 0) ? vv : (vsum[j] + vv);
            }
        }
        __syncthreads();
    }
}

extern "C" void kernel_launch(void* const* d_in, const int* in_sizes, int n_in,
                              void* d_out, int out_size, void* d_ws, size_t ws_size,
                              hipStream_t stream) {
    const float* x    = (const float*)d_in[0];  // [128, 9216]
    const float* W    = (const float*)d_in[1];  // [1152, 10, 16, 8]
    const float* bias = (const float*)d_in[2];  // [1, 1, 10, 16]
    float* out = (float*)d_out;                 // [128, 1, 10, 16, 1]

    const size_t u_bytes  = (size_t)BATCH * 5 * NC1 * 16 * 4;   // 47,185,920
    const size_t s0_bytes = (size_t)BATCH * SDIM * 4;           // 81,920
    const size_t sp_bytes = (size_t)BATCH * 2 * SDIM * 4;       // 163,840
    const size_t need = u_bytes + s0_bytes + 2 * sp_bytes;      // ~47.6 MB

    if (ws_size >= need) {
        unsigned* u_ws  = (unsigned*)d_ws;
        float*    s0    = (float*)((char*)d_ws + u_bytes);
        float*    sp1   = (float*)((char*)d_ws + u_bytes + s0_bytes);
        float*    sp2   = (float*)((char*)d_ws + u_bytes + s0_bytes + sp_bytes);

        caps_zero <<<80, 256, 0, stream>>>(s0);
        caps_uhat <<<dim3(NC1 / CB, BATCH / BB), 256, 0, stream>>>(x, W, u_ws, s0);
        void* args[] = {(void*)&u_ws, (void*)&s0, (void*)&bias,
                        (void*)&sp1, (void*)&sp2, (void*)&out};
        hipLaunchCooperativeKernel((const void*)caps_route2,
                                   dim3(BATCH * 2), dim3(512), args, 0, stream);
    } else {
        caps_fused<<<BATCH, 1024, 0, stream>>>(x, W, bias, out);
    }
}

// Round 14
// 76.788 us; speedup vs baseline: 1.8210x; 1.8210x over previous
//
#include <hip/hip_runtime.h>
#include <hip/hip_fp16.h>

#define BATCH 128
#define NC1   1152
#define ND1   8
#define NC2   10
#define ND2   16
#define SDIM  (NC2 * ND2)    // 160
#define NP    288            // s0 partials per batch elem (72 cb x 4 waves)

// kernel B tiling
#define CB 16                // caps per block
#define BB 32                // batch per block

// pass tiling (round-9 proven): quarters
#define NQ   4
#define QCAP (NC1 / NQ)      // 288

__device__ __forceinline__ unsigned pack_h2(float a, float b) {
    __half2 h = __floats2half2_rn(a, b);
    return *reinterpret_cast<unsigned*>(&h);
}
__device__ __forceinline__ float2 unpack_h2(unsigned v) {
    __half2 h = *reinterpret_cast<__half2*>(&v);
    return __half22float2(h);
}
__device__ __forceinline__ unsigned pmul_h2(unsigned a, unsigned b) {
    __half2 ha = *reinterpret_cast<__half2*>(&a);
    __half2 hb = *reinterpret_cast<__half2*>(&b);
    __half2 r = __hmul2(ha, hb);
    return *reinterpret_cast<unsigned*>(&r);
}
__device__ __forceinline__ unsigned padd_h2(unsigned a, unsigned b) {
    __half2 ha = *reinterpret_cast<__half2*>(&a);
    __half2 hb = *reinterpret_cast<__half2*>(&b);
    __half2 r = __hadd2(ha, hb);
    return *reinterpret_cast<unsigned*>(&r);
}

// DPP row-rotate (within 16-lane row) on the VALU pipe.
template<int CTRL>
__device__ __forceinline__ unsigned dpp_mov(unsigned v) {
    return (unsigned)__builtin_amdgcn_mov_dpp((int)v, CTRL, 0xF, 0xF, true);
}
__device__ __forceinline__ unsigned row_reduce_h2(unsigned t2) {
    t2 = padd_h2(t2, dpp_mov<0x128>(t2));   // ror 8
    t2 = padd_h2(t2, dpp_mov<0x124>(t2));   // ror 4
    t2 = padd_h2(t2, dpp_mov<0x122>(t2));   // ror 2
    t2 = padd_h2(t2, dpp_mov<0x121>(t2));   // ror 1
    return t2;
}

// ---- Kernel B: u_hat (f16x2 -> ws) + s0 partials (NO atomics) -----------
// Round-9 structure (single 80-reg f32 W block, (256,1) -- the only shape
// the allocator keeps resident) + 2-batch ILP: b processed in independent
// pairs to cover exposed latency at 1 wave/SIMD. Pass-0 partial sums are
// plain stores to s0p[b][cb*4+wave][jp][d] (packed f16x2; numerically
// identical to the old padd_h2-then-atomicAdd path).
__global__ __launch_bounds__(256, 1) void caps_uhat(
    const float* __restrict__ x,     // [B, C1*D1]
    const float* __restrict__ W,     // [C1, C2, D2, D1]
    unsigned* __restrict__ u_ws,     // [B][5][C1][16]
    unsigned* __restrict__ s0p)      // [B][NP][5][16] packed f16x2
{
    const int cb  = blockIdx.x;      // 0..71
    const int bb  = blockIdx.y;      // 0..3
    const int tid = threadIdx.x;
    const int cl  = tid >> 4;        // 0..15
    const int d   = tid & 15;
    const int wl  = tid & 63;        // lane in wave
    const int wv  = tid >> 6;        // 0..3

    __shared__ float prim[BB][CB][ND1];  // 16 KB

    for (int i = tid; i < BB * CB; i += 256) {
        const int b = i >> 4, c = i & 15;
        const float* xr = x + ((size_t)(bb * BB + b) * NC1 + (cb * CB + c)) * ND1;
        float4 a0 = *(const float4*)(xr);
        float4 a1 = *(const float4*)(xr + 4);
        float sq = a0.x*a0.x + a0.y*a0.y + a0.z*a0.z + a0.w*a0.w
                 + a1.x*a1.x + a1.y*a1.y + a1.z*a1.z + a1.w*a1.w;
        float g = (sq / (1.0f + sq)) * rsqrtf(sq + 1e-8f);
        prim[b][c][0] = a0.x * g; prim[b][c][1] = a0.y * g;
        prim[b][c][2] = a0.z * g; prim[b][c][3] = a0.w * g;
        prim[b][c][4] = a1.x * g; prim[b][c][5] = a1.y * g;
        prim[b][c][6] = a1.z * g; prim[b][c][7] = a1.w * g;
    }
    __syncthreads();

    const int c_glob = cb * CB + cl;
    float w[NC2][ND1];               // 80 VGPRs, f32 (round-9 exact)
    #pragma unroll
    for (int j = 0; j < NC2; ++j) {
        const float* Wr = W + (((size_t)c_glob * NC2 + j) * ND2 + d) * ND1;
        float4 w0 = *(const float4*)(Wr);
        float4 w1 = *(const float4*)(Wr + 4);
        w[j][0] = w0.x; w[j][1] = w0.y; w[j][2] = w0.z; w[j][3] = w0.w;
        w[j][4] = w1.x; w[j][5] = w1.y; w[j][6] = w1.z; w[j][7] = w1.w;
    }

    const int pid = cb * 4 + wv;     // partial id 0..287

    for (int k = 0; k < BB; k += 2) {
        const int b0 = (k + cb) & (BB - 1);
        const int b1 = (k + 1 + cb) & (BB - 1);
        const int g0 = bb * BB + b0;
        const int g1 = bb * BB + b1;

        float p0[ND1], p1[ND1];
        #pragma unroll
        for (int kk = 0; kk < ND1; ++kk) { p0[kk] = prim[b0][cl][kk];
                                           p1[kk] = prim[b1][cl][kk]; }

        unsigned* ur0 = u_ws + ((size_t)g0 * 5 * NC1 + c_glob) * 16 + d;
        unsigned* ur1 = u_ws + ((size_t)g1 * 5 * NC1 + c_glob) * 16 + d;
        unsigned* q0  = s0p + ((size_t)g0 * NP + pid) * 80 + d;
        unsigned* q1  = s0p + ((size_t)g1 * NP + pid) * 80 + d;

        #pragma unroll
        for (int jp = 0; jp < 5; ++jp) {
            float u00 = 0.f, u01 = 0.f, u10 = 0.f, u11 = 0.f;
            #pragma unroll
            for (int kk = 0; kk < ND1; ++kk) {
                u00 += w[2*jp  ][kk] * p0[kk];
                u01 += w[2*jp+1][kk] * p0[kk];
                u10 += w[2*jp  ][kk] * p1[kk];
                u11 += w[2*jp+1][kk] * p1[kk];
            }
            unsigned pk0 = pack_h2(u00, u01);
            unsigned pk1 = pack_h2(u10, u11);
            ur0[(size_t)jp * (NC1 * 16)] = pk0;
            ur1[(size_t)jp * (NC1 * 16)] = pk1;
            // wave-level partial over the 4 caps (xor16, xor32), then store
            pk0 = padd_h2(pk0, (unsigned)__shfl_xor((int)pk0, 16));
            pk0 = padd_h2(pk0, (unsigned)__shfl_xor((int)pk0, 32));
            pk1 = padd_h2(pk1, (unsigned)__shfl_xor((int)pk1, 16));
            pk1 = padd_h2(pk1, (unsigned)__shfl_xor((int)pk1, 32));
            if (wl < 16) {
                q0[jp * 16] = pk0;
                q1[jp * 16] = pk1;
            }
        }
    }
}

// ---- s0 = sum of the 288 partials (replaces caps_zero + atomics) --------
__global__ void caps_s0sum(const unsigned* __restrict__ s0p,  // [B][NP][80]
                           float* __restrict__ s0) {          // [B][SDIM]
    const int b = blockIdx.x, tid = threadIdx.x;  // 128 thr, 80 active
    if (tid >= 80) return;
    const unsigned* base = s0p + (size_t)b * NP * 80 + tid;
    float sx = 0.f, sy = 0.f;
    #pragma unroll 4
    for (int p = 0; p < NP; ++p) {
        float2 f = unpack_h2(base[(size_t)p * 80]);
        sx += f.x; sy += f.y;
    }
    const int jp = tid >> 4, d = tid & 15;
    s0[(size_t)b * SDIM + jp * 32 + d]      = sx;   // j = 2*jp
    s0[(size_t)b * SDIM + jp * 32 + 16 + d] = sy;   // j = 2*jp+1
}

// ---- one routing pass: partial s per (b, quarter) -- round-9 proven ------
// Grid 512 = (b, q) x 512 thr = 32 groups x 16 lanes; 9 caps/group;
// depth-1 prefetch. DPP row-reduce on the VALU pipe.
// mode 0: v = squash(0.1*s0 + bias)
// mode 1: v = squash(0.1*s0 + bias) + squash(sum(spart_in) + bias)
__global__ __launch_bounds__(512, 1) void caps_pass(
    const unsigned* __restrict__ u_ws,     // [B][5][C1][16] f16x2
    const float* __restrict__ s0,          // [B][SDIM]
    const float* __restrict__ spart_in,    // [B][NQ][SDIM] (mode 1 only)
    const float* __restrict__ bias,        // [SDIM]
    float* __restrict__ spart_out,         // [B][NQ][SDIM]
    int mode)
{
    const int bx   = blockIdx.x;
    const int b    = bx >> 2;
    const int q    = bx & 3;
    const int tid  = threadIdx.x;
    const int grp  = tid >> 4;   // 0..31
    const int d    = tid & 15;
    const int wave = tid >> 6;   // 0..7

    __shared__ float vl[SDIM];
    __shared__ float sred[8][SDIM];

    if (tid < SDIM) {
        float bv = bias[tid];
        float s_a = 0.1f * s0[(size_t)b * SDIM + tid] + bv;
        float qa = s_a * s_a;
        qa += __shfl_xor(qa, 1); qa += __shfl_xor(qa, 2);
        qa += __shfl_xor(qa, 4); qa += __shfl_xor(qa, 8);
        float v = (qa / (1.0f + qa)) * rsqrtf(qa + 1e-8f) * s_a;
        if (mode == 1) {
            float s_b = bv;
            #pragma unroll
            for (int qq = 0; qq < NQ; ++qq)
                s_b += spart_in[((size_t)b * NQ + qq) * SDIM + tid];
            float qb = s_b * s_b;
            qb += __shfl_xor(qb, 1); qb += __shfl_xor(qb, 2);
            qb += __shfl_xor(qb, 4); qb += __shfl_xor(qb, 8);
            v += (qb / (1.0f + qb)) * rsqrtf(qb + 1e-8f) * s_b;
        }
        vl[tid] = v;
    }
    __syncthreads();

    unsigned vsf[5];
    #pragma unroll
    for (int jp = 0; jp < 5; ++jp)
        vsf[jp] = pack_h2(vl[(2*jp)*16 + d], vl[(2*jp+1)*16 + d]);

    const unsigned* ub = u_ws + (size_t)b * 5 * NC1 * 16 + d;
    const int c0 = q * QCAP + grp;       // caps c0 + i*32, i < 9

    float sp[NC2];
    #pragma unroll
    for (int j = 0; j < NC2; ++j) sp[j] = 0.0f;

    unsigned o[5], on[5];
    #pragma unroll
    for (int jp = 0; jp < 5; ++jp)
        o[jp] = ub[(size_t)jp * (NC1 * 16) + (size_t)c0 * 16];

    for (int i = 0; i < 9; ++i) {
        if (i + 1 < 9) {
            const int c = c0 + (i + 1) * 32;
            #pragma unroll
            for (int jp = 0; jp < 5; ++jp)
                on[jp] = ub[(size_t)jp * (NC1 * 16) + (size_t)c * 16];
        }
        float u[NC2], r[NC2];
        #pragma unroll
        for (int jp = 0; jp < 5; ++jp) {
            float2 f = unpack_h2(o[jp]);
            u[2*jp] = f.x; u[2*jp+1] = f.y;
            unsigned t2 = row_reduce_h2(pmul_h2(o[jp], vsf[jp]));  // VALU-only
            float2 rr = unpack_h2(t2);
            r[2*jp] = rr.x; r[2*jp+1] = rr.y;
        }
        float ssum = 0.0f;
        #pragma unroll
        for (int j = 0; j < NC2; ++j) { r[j] = __expf(r[j]); ssum += r[j]; }
        float inv = 1.0f / ssum;
        #pragma unroll
        for (int j = 0; j < NC2; ++j) sp[j] += (r[j] * inv) * u[j];
        #pragma unroll
        for (int jp = 0; jp < 5; ++jp) o[jp] = on[jp];
    }

    #pragma unroll
    for (int j = 0; j < NC2; ++j) {
        sp[j] += __shfl_xor(sp[j], 16);
        sp[j] += __shfl_xor(sp[j], 32);
    }
    if ((tid & 63) < 16) {
        #pragma unroll
        for (int j = 0; j < NC2; ++j) sred[wave][j * 16 + d] = sp[j];
    }
    __syncthreads();
    if (tid < SDIM) {
        float acc = 0.0f;
        #pragma unroll
        for (int w = 0; w < 8; ++w) acc += sred[w][tid];
        spart_out[((size_t)b * NQ + q) * SDIM + tid] = acc;
    }
}

// ---- final combine: out = squash(sum spart2 + bias) ----------------------
__global__ void caps_comb2(const float* __restrict__ spart,
                           const float* __restrict__ bias,
                           float* __restrict__ out) { // grid 128 x 192
    const int b = blockIdx.x, tid = threadIdx.x;
    if (tid >= SDIM) return;
    float s = bias[tid];
    #pragma unroll
    for (int q = 0; q < NQ; ++q)
        s += spart[((size_t)b * NQ + q) * SDIM + tid];
    float sq = s * s;
    sq += __shfl_xor(sq, 1); sq += __shfl_xor(sq, 2);
    sq += __shfl_xor(sq, 4); sq += __shfl_xor(sq, 8);
    out[(size_t)b * SDIM + tid] = (sq / (1.0f + sq)) * rsqrtf(sq + 1e-8f) * s;
}

// ---- Fallback: round-1 fused kernel (proven, 198 us) ---------------------
__global__ __launch_bounds__(1024) void caps_fused(
    const float* __restrict__ x, const float* __restrict__ W,
    const float* __restrict__ bias, float* __restrict__ out)
{
    const int b    = blockIdx.x;
    const int tid  = threadIdx.x;
    const int grp  = tid >> 4;
    const int d    = tid & 15;
    const int wave = tid >> 6;
    const int lane = tid & 63;

    __shared__ float prim[NC1][ND1];
    __shared__ float sred[16][SDIM];
    __shared__ float vbuf[SDIM];

    const float* xb = x + (size_t)b * (NC1 * ND1);
    for (int c = tid; c < NC1; c += 1024) {
        float4 a0 = *(const float4*)(xb + c * 8);
        float4 a1 = *(const float4*)(xb + c * 8 + 4);
        float sq = a0.x*a0.x + a0.y*a0.y + a0.z*a0.z + a0.w*a0.w
                 + a1.x*a1.x + a1.y*a1.y + a1.z*a1.z + a1.w*a1.w;
        float g = (sq / (1.0f + sq)) * rsqrtf(sq + 1e-8f);
        prim[c][0] = a0.x * g; prim[c][1] = a0.y * g;
        prim[c][2] = a0.z * g; prim[c][3] = a0.w * g;
        prim[c][4] = a1.x * g; prim[c][5] = a1.y * g;
        prim[c][6] = a1.z * g; prim[c][7] = a1.w * g;
    }
    __syncthreads();

    float vsum[NC2], sp[NC2];
    for (int pass = 0; pass < 3; ++pass) {
        #pragma unroll
        for (int j = 0; j < NC2; ++j) sp[j] = 0.0f;
        for (int c = grp; c < NC1; c += 64) {
            float p[8];
            #pragma unroll
            for (int k = 0; k < 8; ++k) p[k] = prim[c][k];
            const float* Wc = W + (size_t)c * (NC2 * ND2 * ND1) + d * ND1;
            float u[NC2];
            #pragma unroll
            for (int j = 0; j < NC2; ++j) {
                const float4 w0 = *(const float4*)(Wc + j * (ND2 * ND1));
                const float4 w1 = *(const float4*)(Wc + j * (ND2 * ND1) + 4);
                u[j] = w0.x*p[0] + w0.y*p[1] + w0.z*p[2] + w0.w*p[3]
                     + w1.x*p[4] + w1.y*p[5] + w1.z*p[6] + w1.w*p[7];
            }
            if (pass == 0) {
                #pragma unroll
                for (int j = 0; j < NC2; ++j) sp[j] += u[j];
            } else {
                float r[NC2];
                #pragma unroll
                for (int j = 0; j < NC2; ++j) {
                    float t = u[j] * vsum[j];
                    t += __shfl_xor(t, 1); t += __shfl_xor(t, 2);
                    t += __shfl_xor(t, 4); t += __shfl_xor(t, 8);
                    r[j] = t;
                }
                float m = r[0];
                #pragma unroll
                for (int j = 1; j < NC2; ++j) m = fmaxf(m, r[j]);
                float ssum = 0.0f;
                #pragma unroll
                for (int j = 0; j < NC2; ++j) { r[j] = __expf(r[j] - m); ssum += r[j]; }
                float inv = 1.0f / ssum;
                #pragma unroll
                for (int j = 0; j < NC2; ++j) sp[j] += (r[j] * inv) * u[j];
            }
        }
        #pragma unroll
        for (int j = 0; j < NC2; ++j) {
            sp[j] += __shfl_xor(sp[j], 16);
            sp[j] += __shfl_xor(sp[j], 32);
        }
        if (lane < 16) {
            #pragma unroll
            for (int j = 0; j < NC2; ++j) sred[wave][j * 16 + d] = sp[j];
        }
        __syncthreads();
        if (tid < SDIM) {
            float acc = 0.0f;
            #pragma unroll
            for (int w = 0; w < 16; ++w) acc += sred[w][tid];
            float s = bias[tid] + (pass == 0 ? 0.1f * acc : acc);
            float sq = s * s;
            sq += __shfl_xor(sq, 1); sq += __shfl_xor(sq, 2);
            sq += __shfl_xor(sq, 4); sq += __shfl_xor(sq, 8);
            float vv = (sq / (1.0f + sq)) * rsqrtf(sq + 1e-8f) * s;
            if (pass == 2) out[(size_t)b * SDIM + tid] = vv;
            else           vbuf[tid] = vv;
        }
        __syncthreads();
        if (pass < 2) {
            #pragma unroll
            for (int j = 0; j < NC2; ++j) {
                float vv = vbuf[j * 16 + d];
                vsum[j] = (pass == 0) ? vv : (vsum[j] + vv);
            }
        }
        __syncthreads();
    }
}

extern "C" void kernel_launch(void* const* d_in, const int* in_sizes, int n_in,
                              void* d_out, int out_size, void* d_ws, size_t ws_size,
                              hipStream_t stream) {
    const float* x    = (const float*)d_in[0];  // [128, 9216]
    const float* W    = (const float*)d_in[1];  // [1152, 10, 16, 8]
    const float* bias = (const float*)d_in[2];  // [1, 1, 10, 16]
    float* out = (float*)d_out;                 // [128, 1, 10, 16, 1]

    const size_t u_bytes   = (size_t)BATCH * 5 * NC1 * 16 * 4;   // 47,185,920
    const size_t s0p_bytes = (size_t)BATCH * NP * 80 * 4;        // 11,796,480
    const size_t s0_bytes  = (size_t)BATCH * SDIM * 4;           // 81,920
    const size_t sp_bytes  = (size_t)BATCH * NQ * SDIM * 4;      // 327,680
    const size_t need = u_bytes + s0p_bytes + s0_bytes + 2 * sp_bytes; // ~59.7 MB
    // (harness fills show d_ws is ~256 MiB; fused fallback covers the rest)

    if (ws_size >= need) {
        char* p = (char*)d_ws;
        unsigned* u_ws = (unsigned*)p;                    p += u_bytes;
        unsigned* s0p  = (unsigned*)p;                    p += s0p_bytes;
        float*    s0   = (float*)p;                       p += s0_bytes;
        float*    sp1  = (float*)p;                       p += sp_bytes;
        float*    sp2  = (float*)p;

        caps_uhat <<<dim3(NC1 / CB, BATCH / BB), 256, 0, stream>>>(x, W, u_ws, s0p);
        caps_s0sum<<<BATCH, 128, 0, stream>>>(s0p, s0);
        caps_pass <<<BATCH * NQ, 512, 0, stream>>>(u_ws, s0, sp1, bias, sp1, 0);
        caps_pass <<<BATCH * NQ, 512, 0, stream>>>(u_ws, s0, sp1, bias, sp2, 1);
        caps_comb2<<<BATCH, 192, 0, stream>>>(sp2, bias, out);
    } else {
        caps_fused<<<BATCH, 1024, 0, stream>>>(x, W, bias, out);
    }
}